// Round 4
// baseline (1581.024 us; speedup 1.0000x reference)
//
#include <hip/hip_runtime.h>
#include <hip/hip_bf16.h>

#define NN 50000
#define NE 1600000
#define NR 16
#define TM 32                    // dst rows per block tile
#define NTILE 1563               // ceil(NN/TM)
#define NB2 (NR * NTILE)         // 25008 coarse bins (rel, dtile)
#define NBP 25088                // padded to 98*256
#define NSCB 98

typedef __bf16 bf16x8 __attribute__((ext_vector_type(8)));
typedef unsigned short u16x8 __attribute__((ext_vector_type(8)));
typedef float f32x4 __attribute__((ext_vector_type(4)));

__device__ __forceinline__ unsigned short f2bf(float f) {
    union { float f; unsigned int u; } v; v.f = f;
    unsigned int u = v.u;
    u += 0x7FFFu + ((u >> 16) & 1u);
    return (unsigned short)(u >> 16);
}
__device__ __forceinline__ float bflo(unsigned int u) {
    union { unsigned int u; float f; } v; v.u = u << 16; return v.f;
}
__device__ __forceinline__ float bfhi(unsigned int u) {
    union { unsigned int u; float f; } v; v.u = u & 0xFFFF0000u; return v.f;
}

// ---------------- prep ----------------------------------------------------

__global__ __launch_bounds__(256) void prep_h(const int* __restrict__ node_ids,
                                              const float* __restrict__ emb,
                                              unsigned short* __restrict__ h_bf) {
    int gid = blockIdx.x * 256 + threadIdx.x;
    if (gid >= NN * 32) return;
    int row = gid >> 5;
    int c = (gid & 31) << 2;
    int nid = node_ids[row];
    if (nid < 0) nid = 0; if (nid >= NN) nid = NN - 1;
    float4 v = *(const float4*)(emb + (size_t)nid * 128 + c);
    ushort4 o;
    o.x = f2bf(v.x); o.y = f2bf(v.y); o.z = f2bf(v.z); o.w = f2bf(v.w);
    *(ushort4*)(h_bf + (size_t)row * 128 + c) = o;
}

// Wt[r][o][k] = bf16(W[r][k][o])
__global__ __launch_bounds__(256) void prep_w(const float* __restrict__ W,
                                              unsigned short* __restrict__ Wt) {
    int gid = blockIdx.x * 256 + threadIdx.x;
    if (gid >= NR * 128 * 128) return;
    int r = gid >> 14;
    int idx = gid & 16383;
    int k = idx >> 7;
    int o = idx & 127;
    Wt[(size_t)r * 16384 + (size_t)o * 128 + k] = f2bf(W[gid]);
}

// ---------------- coarse counting sort by (rel, dtile) --------------------

__global__ __launch_bounds__(256) void hist_key(const int* __restrict__ dst,
                                                const int* __restrict__ rel,
                                                int* __restrict__ counts) {
    int e = blockIdx.x * 256 + threadIdx.x;
    if (e >= NE) return;
    atomicAdd(&counts[rel[e] * NTILE + (dst[e] >> 5)], 1);
}

__global__ __launch_bounds__(256) void scanA(const int* __restrict__ counts,
                                             int* __restrict__ blockSums) {
    __shared__ int s[256];
    int t = threadIdx.x;
    s[t] = counts[blockIdx.x * 256 + t];
    __syncthreads();
    for (int off = 128; off > 0; off >>= 1) {
        if (t < off) s[t] += s[t + off];
        __syncthreads();
    }
    if (t == 0) blockSums[blockIdx.x] = s[0];
}

__global__ __launch_bounds__(256) void scanB(int* __restrict__ bs) {
    __shared__ int s[256];
    int t = threadIdx.x;
    int v = (t < NSCB) ? bs[t] : 0;
    s[t] = v;
    __syncthreads();
    for (int off = 1; off < 256; off <<= 1) {
        int x = (t >= off) ? s[t - off] : 0;
        __syncthreads();
        s[t] += x;
        __syncthreads();
    }
    if (t < NSCB) bs[t] = s[t] - v;
}

__global__ __launch_bounds__(256) void scanC(int* __restrict__ counts,
                                             const int* __restrict__ bs,
                                             int* __restrict__ start2) {
    __shared__ int s[256];
    int t = threadIdx.x;
    int idx = blockIdx.x * 256 + t;
    int v = counts[idx];
    s[t] = v;
    __syncthreads();
    for (int off = 1; off < 256; off <<= 1) {
        int x = (t >= off) ? s[t - off] : 0;
        __syncthreads();
        s[t] += x;
        __syncthreads();
    }
    int excl = bs[blockIdx.x] + s[t] - v;
    start2[idx] = excl;
    counts[idx] = excl;            // cursor for scatter_rank
}

// rec = (src | localrow<<16, norm), grouped by (rel, dtile)
__global__ __launch_bounds__(256) void scatter_rank(const int* __restrict__ src,
                                                    const int* __restrict__ dst,
                                                    const int* __restrict__ rel,
                                                    const float* __restrict__ norm,
                                                    int* __restrict__ cursor,
                                                    uint2* __restrict__ recs) {
    int e = blockIdx.x * 256 + threadIdx.x;
    if (e >= NE) return;
    int d = dst[e];
    int key = rel[e] * NTILE + (d >> 5);
    int pos = atomicAdd(&cursor[key], 1);
    recs[pos] = make_uint2((unsigned int)src[e] | ((unsigned int)(d & 31) << 16),
                           __float_as_uint(norm[e]));
}

// ---------------- fused aggregate + transform -----------------------------
// Per block (32 dst rows x 128 out), per rel: zero fp32 A-tile + stage Wt[r]
// to LDS; 16 records processed concurrently (4 waves x 4 groups of 16 lanes;
// group gathers one 256B h row, LDS-f32-atomic accumulate); then MFMA,
// C accumulated in registers across all 16 rels.
// sAf phys layout: col 8m+t stored at [row*132 + m + 16t] (m=0..15,t=0..7)
// -> build atomics and A-frag reads are conflict-benign.
__global__ __launch_bounds__(256, 3) void rgcn_fused(
        const int* __restrict__ start2,
        const uint2* __restrict__ recs,
        const uint4* __restrict__ hb4,        // h_bf rows as 16 uint4
        const unsigned short* __restrict__ Wt,
        float* __restrict__ out) {
    __shared__ __attribute__((aligned(16))) float sAf[TM * 132];          // 16.9 KB
    __shared__ __attribute__((aligned(16))) unsigned short sW[128 * 136]; // 34.8 KB
    const int t = threadIdx.x;
    const int lane = t & 63;
    const int w = t >> 6;
    const int g = lane >> 4;          // record-group within wave
    const int m = lane & 15;          // lane within group
    const int l15 = lane & 15, lhi = lane >> 4;
    const int mrow = (w & 1) * 16;
    const int ncol = (w >> 1) * 64;
    const int dtile = blockIdx.x * TM;

    f32x4 acc[4];
    #pragma unroll
    for (int nt = 0; nt < 4; ++nt) acc[nt] = (f32x4){0.f, 0.f, 0.f, 0.f};

    for (int r = 0; r < NR; ++r) {
        // ---- phase 1: zero A-tile + stage Wt[r] -> sW
        #pragma unroll
        for (int i = 0; i < 5; ++i) {
            int c = t + i * 256;
            if (c < TM * 132 / 4)
                *(float4*)&sAf[c * 4] = make_float4(0.f, 0.f, 0.f, 0.f);
        }
        const unsigned short* wrp = Wt + ((size_t)r << 14);
        #pragma unroll
        for (int it = 0; it < 8; ++it) {
            int c = t + it * 256;
            int row = c >> 4, c8 = (c & 15) << 3;
            uint4 v = *(const uint4*)(wrp + row * 128 + c8);
            *(uint4*)&sW[row * 136 + c8] = v;
        }
        __syncthreads();

        // ---- phase 2: edge-parallel build (16 records in flight per block)
        int bin = r * NTILE + blockIdx.x;
        int beg = start2[bin], end = start2[bin + 1];
        for (int base = beg + w * 16; base < end; base += 64) {
            int lim = end - base; if (lim > 16) lim = 16;
            uint2 rc = make_uint2(0u, 0u);
            if (lane < lim) rc = recs[base + lane];
            for (int j = 0; j < lim; j += 4) {
                int ridx = j + g;
                unsigned int rx = (unsigned int)__shfl((int)rc.x, ridx & 15);
                float nm = __uint_as_float(__shfl((int)rc.y, ridx & 15));
                if (ridx < lim) {
                    int srcn = (int)(rx & 0xFFFFu);
                    int row = (int)(rx >> 16);
                    uint4 u = hb4[(size_t)srcn * 16 + m];
                    float* rp = sAf + row * 132 + m;
                    atomicAdd(rp,       bflo(u.x) * nm);
                    atomicAdd(rp + 16,  bfhi(u.x) * nm);
                    atomicAdd(rp + 32,  bflo(u.y) * nm);
                    atomicAdd(rp + 48,  bfhi(u.y) * nm);
                    atomicAdd(rp + 64,  bflo(u.z) * nm);
                    atomicAdd(rp + 80,  bfhi(u.z) * nm);
                    atomicAdd(rp + 96,  bflo(u.w) * nm);
                    atomicAdd(rp + 112, bfhi(u.w) * nm);
                }
            }
        }
        __syncthreads();

        // ---- phase 3: MFMA (A from sAf fp32 -> bf16 in regs, B from sW)
        #pragma unroll
        for (int kt = 0; kt < 4; ++kt) {
            const int K = kt * 4 + lhi;          // ko/8
            const int ko = kt * 32 + lhi * 8;
            bf16x8 aF;
            #pragma unroll
            for (int j = 0; j < 8; ++j)
                aF[j] = (__bf16)sAf[(mrow + l15) * 132 + K + 16 * j];
            #pragma unroll
            for (int nt = 0; nt < 4; ++nt) {
                u16x8 braw = *(const u16x8*)&sW[(ncol + nt * 16 + l15) * 136 + ko];
                acc[nt] = __builtin_amdgcn_mfma_f32_16x16x32_bf16(
                        aF, __builtin_bit_cast(bf16x8, braw), acc[nt], 0, 0, 0);
            }
        }
        __syncthreads();   // protects sAf/sW for next rel's phase 1
    }

    // ---- epilogue: D layout col=lane&15, row=(lane>>4)*4+reg
    #pragma unroll
    for (int reg = 0; reg < 4; ++reg) {
        int d = dtile + mrow + lhi * 4 + reg;
        if (d < NN) {
            #pragma unroll
            for (int nt = 0; nt < 4; ++nt)
                out[(size_t)d * 128 + ncol + nt * 16 + l15] = acc[nt][reg];
        }
    }
}

// ---------------- launch ---------------------------------------------------

extern "C" void kernel_launch(void* const* d_in, const int* in_sizes, int n_in,
                              void* d_out, int out_size, void* d_ws, size_t ws_size,
                              hipStream_t stream) {
    const int* node_ids = (const int*)d_in[0];
    const int* src      = (const int*)d_in[1];
    const int* dst      = (const int*)d_in[2];
    const int* rel      = (const int*)d_in[3];
    const float* norm   = (const float*)d_in[4];
    const float* emb    = (const float*)d_in[5];
    const float* W      = (const float*)d_in[6];
    float* out = (float*)d_out;

    char* ws = (char*)d_ws;
    unsigned short* h_bf = (unsigned short*)(ws);              // 12,800,000 B
    uint2* recs          = (uint2*)(ws + 12800000);            // 12,800,000 B
    unsigned short* Wt   = (unsigned short*)(ws + 25600000);   //    524,288 B
    int* counts          = (int*)(ws + 26124288);              //    100,352 B (NBP)
    int* start2          = (int*)(ws + 26224640);              //    100,356 B (NBP+1)
    int* blockSums       = (int*)(ws + 26325000);              //        392 B
    // total ~26.3 MB

    hipMemsetAsync(counts, 0, (size_t)NBP * sizeof(int), stream);

    prep_h<<<6250, 256, 0, stream>>>(node_ids, emb, h_bf);
    prep_w<<<(NR * 128 * 128 + 255) / 256, 256, 0, stream>>>(W, Wt);
    hist_key<<<(NE + 255) / 256, 256, 0, stream>>>(dst, rel, counts);
    scanA<<<NSCB, 256, 0, stream>>>(counts, blockSums);
    scanB<<<1, 256, 0, stream>>>(blockSums);
    scanC<<<NSCB, 256, 0, stream>>>(counts, blockSums, start2);
    scatter_rank<<<(NE + 255) / 256, 256, 0, stream>>>(src, dst, rel, norm,
                                                       counts, recs);
    rgcn_fused<<<NTILE, 256, 0, stream>>>(start2, recs,
                                          (const uint4*)h_bf, Wt, out);
}

// Round 5
// 426.496 us; speedup vs baseline: 3.7070x; 3.7070x over previous
//
#include <hip/hip_runtime.h>
#include <hip/hip_bf16.h>

#define NN 50000
#define NE 1600000
#define HD 128
#define OD 128
#define NR 16

typedef __bf16 bf16x8 __attribute__((ext_vector_type(8)));
typedef unsigned short u16x8 __attribute__((ext_vector_type(8)));
typedef float f32x4 __attribute__((ext_vector_type(4)));

__device__ __forceinline__ unsigned short f2bf(float f) {
    union { float f; unsigned int u; } v; v.f = f;
    unsigned int u = v.u;
    u += 0x7FFFu + ((u >> 16) & 1u);   // round-to-nearest-even
    return (unsigned short)(u >> 16);
}
__device__ __forceinline__ float bflo(unsigned int u) {
    union { unsigned int u; float f; } v; v.u = u << 16; return v.f;
}
__device__ __forceinline__ float bfhi(unsigned int u) {
    union { unsigned int u; float f; } v; v.u = u & 0xFFFF0000u; return v.f;
}

// ---------------- phase 1: transform -------------------------------------

// h_bf[n][k] = bf16(emb[node_ids[n]][k])
__global__ __launch_bounds__(256) void prep_h(const int* __restrict__ node_ids,
                                              const float* __restrict__ emb,
                                              unsigned short* __restrict__ h_bf) {
    int gid = blockIdx.x * 256 + threadIdx.x;
    if (gid >= NN * 32) return;
    int row = gid >> 5;
    int c = (gid & 31) << 2;
    int nid = node_ids[row];
    if (nid < 0) nid = 0; if (nid >= NN) nid = NN - 1;
    float4 v = *(const float4*)(emb + (size_t)nid * HD + c);
    ushort4 o;
    o.x = f2bf(v.x); o.y = f2bf(v.y); o.z = f2bf(v.z); o.w = f2bf(v.w);
    *(ushort4*)(h_bf + (size_t)row * HD + c) = o;
}

// Wt[r][o][k] = bf16(W[r][k][o])
__global__ __launch_bounds__(256) void prep_w(const float* __restrict__ W,
                                              unsigned short* __restrict__ Wt) {
    int gid = blockIdx.x * 256 + threadIdx.x;
    if (gid >= NR * HD * OD) return;
    int r = gid >> 14;
    int idx = gid & 16383;
    int k = idx >> 7;
    int o = idx & 127;
    Wt[(size_t)r * 16384 + (size_t)o * 128 + k] = f2bf(W[gid]);
}

// GEMM: h_rel[r][n][o] = sum_k h_bf[n][k] * W[r][k][o], stored bf16.
// (round-2 structure: proven ~fast, never in top-5 at 548 µs total)
__global__ __launch_bounds__(256) void gemm_hrel(const unsigned short* __restrict__ h_bf,
                                                 const unsigned short* __restrict__ Wt,
                                                 unsigned short* __restrict__ h_rel) {
    __shared__ unsigned short sA[128][136];
    __shared__ unsigned short sB[128][136];
    const int t = threadIdx.x;
    const int tile = blockIdx.x;
    const int r = blockIdx.y;
    const int base = tile * 128;

    #pragma unroll
    for (int j = 0; j < 8; ++j) {
        int idx = t + j * 256;
        int row = idx >> 4;
        int c8 = (idx & 15) << 3;
        int g = base + row;
        if (g >= NN) g = 0;
        uint4 v = *(const uint4*)(h_bf + (size_t)g * 128 + c8);
        *(uint4*)&sA[row][c8] = v;
    }
    const unsigned short* wp = Wt + (size_t)r * 16384;
    #pragma unroll
    for (int j = 0; j < 8; ++j) {
        int idx = t + j * 256;
        int row = idx >> 4;
        int c8 = (idx & 15) << 3;
        uint4 v = *(const uint4*)(wp + (size_t)row * 128 + c8);
        *(uint4*)&sB[row][c8] = v;
    }
    __syncthreads();

    const int lane = t & 63;
    const int w = t >> 6;
    const int wr = w >> 1, wc = w & 1;
    const int l15 = lane & 15, lhi = lane >> 4;

    f32x4 acc[4][4];
    #pragma unroll
    for (int i = 0; i < 4; ++i)
        #pragma unroll
        for (int j = 0; j < 4; ++j)
            acc[i][j] = (f32x4){0.f, 0.f, 0.f, 0.f};

    #pragma unroll
    for (int kt = 0; kt < 4; ++kt) {
        const int ko = kt * 32 + lhi * 8;
        bf16x8 aF[4], bF[4];
        #pragma unroll
        for (int ms = 0; ms < 4; ++ms) {
            u16x8 raw = *(const u16x8*)&sA[wr * 64 + ms * 16 + l15][ko];
            aF[ms] = __builtin_bit_cast(bf16x8, raw);
        }
        #pragma unroll
        for (int nt = 0; nt < 4; ++nt) {
            u16x8 raw = *(const u16x8*)&sB[wc * 64 + nt * 16 + l15][ko];
            bF[nt] = __builtin_bit_cast(bf16x8, raw);
        }
        #pragma unroll
        for (int ms = 0; ms < 4; ++ms)
            #pragma unroll
            for (int nt = 0; nt < 4; ++nt)
                acc[ms][nt] = __builtin_amdgcn_mfma_f32_16x16x32_bf16(
                    aF[ms], bF[nt], acc[ms][nt], 0, 0, 0);
    }

    #pragma unroll
    for (int ms = 0; ms < 4; ++ms) {
        #pragma unroll
        for (int reg = 0; reg < 4; ++reg) {
            int m = base + wr * 64 + ms * 16 + lhi * 4 + reg;
            if (m < NN) {
                size_t rowp = ((size_t)r * NN + m) * 128;
                #pragma unroll
                for (int nt = 0; nt < 4; ++nt) {
                    int o = wc * 64 + nt * 16 + l15;
                    h_rel[rowp + o] = f2bf(acc[ms][nt][reg]);
                }
            }
        }
    }
}

// ---------------- phase 2: counting sort by dst ---------------------------

__global__ __launch_bounds__(256) void hist_dst(const int* __restrict__ dst,
                                                int* __restrict__ counts) {
    int e = blockIdx.x * 256 + threadIdx.x;
    if (e >= NE) return;
    atomicAdd(&counts[dst[e]], 1);
}

__global__ __launch_bounds__(256) void scanA(const int* __restrict__ counts,
                                             int* __restrict__ blockSums) {
    __shared__ int s[256];
    int t = threadIdx.x;
    int idx = blockIdx.x * 256 + t;
    s[t] = (idx < NN) ? counts[idx] : 0;
    __syncthreads();
    for (int off = 128; off > 0; off >>= 1) {
        if (t < off) s[t] += s[t + off];
        __syncthreads();
    }
    if (t == 0) blockSums[blockIdx.x] = s[0];
}

__global__ __launch_bounds__(256) void scanB(int* __restrict__ blockSums) {
    __shared__ int s[256];
    int t = threadIdx.x;
    int v = (t < 196) ? blockSums[t] : 0;
    s[t] = v;
    __syncthreads();
    for (int off = 1; off < 256; off <<= 1) {
        int x = (t >= off) ? s[t - off] : 0;
        __syncthreads();
        s[t] += x;
        __syncthreads();
    }
    if (t < 196) blockSums[t] = s[t] - v;   // exclusive
}

__global__ __launch_bounds__(256) void scanC(const int* __restrict__ counts,
                                             const int* __restrict__ blockSums,
                                             int* __restrict__ start,
                                             int* __restrict__ cursor) {
    __shared__ int s[256];
    int t = threadIdx.x;
    int idx = blockIdx.x * 256 + t;
    int v = (idx < NN) ? counts[idx] : 0;
    s[t] = v;
    __syncthreads();
    for (int off = 1; off < 256; off <<= 1) {
        int x = (t >= off) ? s[t - off] : 0;
        __syncthreads();
        s[t] += x;
        __syncthreads();
    }
    if (idx < NN) {
        int excl = blockSums[blockIdx.x] + s[t] - v;
        start[idx] = excl;
        cursor[idx] = excl;
    }
    if (idx == 0) start[NN] = NE;
}

// pre-joined record: (src | rel<<16, norm) in dst-sorted order
__global__ __launch_bounds__(256) void scatter_rank(const int* __restrict__ src,
                                                    const int* __restrict__ dst,
                                                    const int* __restrict__ rel,
                                                    const float* __restrict__ norm,
                                                    int* __restrict__ cursor,
                                                    uint2* __restrict__ recs) {
    int e = blockIdx.x * 256 + threadIdx.x;
    if (e >= NE) return;
    int pos = atomicAdd(&cursor[dst[e]], 1);
    recs[pos] = make_uint2((unsigned int)src[e] |
                           ((unsigned int)rel[e] << 16),
                           __float_as_uint(norm[e]));
}

// ---------------- phase 3: segmented reduction ----------------------------
// one wave per dst node; lane owns 2 output cols (one h_rel dword).
// 2-level chain (recs -> h_rel), unroll-4 for >=4 gathers in flight.
__global__ __launch_bounds__(256) void seg_reduce(const int* __restrict__ start,
                                                  const uint2* __restrict__ recs,
                                                  const unsigned int* __restrict__ hb,
                                                  float* __restrict__ out) {
    int gid = blockIdx.x * 256 + threadIdx.x;
    int d = gid >> 6;
    if (d >= NN) return;
    int lane = gid & 63;
    int beg = start[d], end = start[d + 1];
    float a0 = 0.f, a1 = 0.f;
    int i = beg;
    for (; i + 3 < end; i += 4) {
        uint2 rc0 = recs[i];
        uint2 rc1 = recs[i + 1];
        uint2 rc2 = recs[i + 2];
        uint2 rc3 = recs[i + 3];
        unsigned int u0 = hb[(((size_t)(rc0.x >> 16) * NN + (rc0.x & 0xFFFFu)) << 6) + lane];
        unsigned int u1 = hb[(((size_t)(rc1.x >> 16) * NN + (rc1.x & 0xFFFFu)) << 6) + lane];
        unsigned int u2 = hb[(((size_t)(rc2.x >> 16) * NN + (rc2.x & 0xFFFFu)) << 6) + lane];
        unsigned int u3 = hb[(((size_t)(rc3.x >> 16) * NN + (rc3.x & 0xFFFFu)) << 6) + lane];
        float n0 = __uint_as_float(rc0.y), n1 = __uint_as_float(rc1.y);
        float n2 = __uint_as_float(rc2.y), n3 = __uint_as_float(rc3.y);
        a0 += bflo(u0) * n0 + bflo(u1) * n1 + bflo(u2) * n2 + bflo(u3) * n3;
        a1 += bfhi(u0) * n0 + bfhi(u1) * n1 + bfhi(u2) * n2 + bfhi(u3) * n3;
    }
    for (; i < end; ++i) {
        uint2 rc = recs[i];
        unsigned int u = hb[(((size_t)(rc.x >> 16) * NN + (rc.x & 0xFFFFu)) << 6) + lane];
        float nm = __uint_as_float(rc.y);
        a0 += bflo(u) * nm;
        a1 += bfhi(u) * nm;
    }
    *(float2*)(out + (size_t)d * 128 + lane * 2) = make_float2(a0, a1);
}

// ---------------- launch ---------------------------------------------------

extern "C" void kernel_launch(void* const* d_in, const int* in_sizes, int n_in,
                              void* d_out, int out_size, void* d_ws, size_t ws_size,
                              hipStream_t stream) {
    const int* node_ids = (const int*)d_in[0];
    const int* src      = (const int*)d_in[1];
    const int* dst      = (const int*)d_in[2];
    const int* rel      = (const int*)d_in[3];
    const float* norm   = (const float*)d_in[4];
    const float* emb    = (const float*)d_in[5];
    const float* W      = (const float*)d_in[6];
    float* out = (float*)d_out;

    char* ws = (char*)d_ws;
    unsigned short* h_rel = (unsigned short*)(ws);                 // 204,800,000 B
    unsigned short* h_bf  = (unsigned short*)(ws + 204800000);     //  12,800,000 B
    uint2* recs           = (uint2*)(ws + 204800000);              // ALIAS of h_bf
                                                                   // (written only after gemm_hrel)
    unsigned short* Wt    = (unsigned short*)(ws + 217600000);     //     524,288 B
    int* counts           = (int*)(ws + 218124288);                //     200,704 B
    int* start            = (int*)(ws + 218324992);                //     200,708 B
    int* cursor           = (int*)(ws + 218525696);                //     200,704 B
    int* blockSums        = (int*)(ws + 218726400);                //       1,024 B

    hipMemsetAsync(counts, 0, 50176 * sizeof(int), stream);

    prep_h<<<6250, 256, 0, stream>>>(node_ids, emb, h_bf);
    prep_w<<<(NR * HD * OD + 255) / 256, 256, 0, stream>>>(W, Wt);
    hist_dst<<<(NE + 255) / 256, 256, 0, stream>>>(dst, counts);
    scanA<<<196, 256, 0, stream>>>(counts, blockSums);
    scanB<<<1, 256, 0, stream>>>(blockSums);
    scanC<<<196, 256, 0, stream>>>(counts, blockSums, start, cursor);

    gemm_hrel<<<dim3(391, NR), 256, 0, stream>>>(h_bf, Wt, h_rel);

    // recs aliases h_bf — must run after gemm_hrel (stream-serial: ok)
    scatter_rank<<<(NE + 255) / 256, 256, 0, stream>>>(src, dst, rel, norm,
                                                       cursor, recs);

    seg_reduce<<<(NN * 64 + 255) / 256, 256, 0, stream>>>(start, recs,
                                                          (const unsigned int*)h_rel,
                                                          out);
}

// Round 6
// 362.810 us; speedup vs baseline: 4.3577x; 1.1755x over previous
//
#include <hip/hip_runtime.h>
#include <hip/hip_bf16.h>

#define NN 50000
#define NE 1600000
#define HD 128
#define OD 128
#define NR 16

typedef __bf16 bf16x8 __attribute__((ext_vector_type(8)));
typedef unsigned short u16x8 __attribute__((ext_vector_type(8)));
typedef float f32x4 __attribute__((ext_vector_type(4)));

__device__ __forceinline__ unsigned short f2bf(float f) {
    union { float f; unsigned int u; } v; v.f = f;
    unsigned int u = v.u;
    u += 0x7FFFu + ((u >> 16) & 1u);   // round-to-nearest-even
    return (unsigned short)(u >> 16);
}
__device__ __forceinline__ float bflo(unsigned int u) {
    union { unsigned int u; float f; } v; v.u = u << 16; return v.f;
}
__device__ __forceinline__ float bfhi(unsigned int u) {
    union { unsigned int u; float f; } v; v.u = u & 0xFFFF0000u; return v.f;
}

// ---------------- phase 1: transform -------------------------------------

// h_bf[n][k] = bf16(emb[node_ids[n]][k])
__global__ __launch_bounds__(256) void prep_h(const int* __restrict__ node_ids,
                                              const float* __restrict__ emb,
                                              unsigned short* __restrict__ h_bf) {
    int gid = blockIdx.x * 256 + threadIdx.x;
    if (gid >= NN * 32) return;
    int row = gid >> 5;
    int c = (gid & 31) << 2;
    int nid = node_ids[row];
    if (nid < 0) nid = 0; if (nid >= NN) nid = NN - 1;
    float4 v = *(const float4*)(emb + (size_t)nid * HD + c);
    ushort4 o;
    o.x = f2bf(v.x); o.y = f2bf(v.y); o.z = f2bf(v.z); o.w = f2bf(v.w);
    *(ushort4*)(h_bf + (size_t)row * HD + c) = o;
}

// Wt[r][o][k] = bf16(W[r][k][o])
__global__ __launch_bounds__(256) void prep_w(const float* __restrict__ W,
                                              unsigned short* __restrict__ Wt) {
    int gid = blockIdx.x * 256 + threadIdx.x;
    if (gid >= NR * HD * OD) return;
    int r = gid >> 14;
    int idx = gid & 16383;
    int k = idx >> 7;
    int o = idx & 127;
    Wt[(size_t)r * 16384 + (size_t)o * 128 + k] = f2bf(W[gid]);
}

// GEMM: h_rel[r][n][o] = sum_k h_bf[n][k] * W[r][k][o], stored bf16.
__global__ __launch_bounds__(256) void gemm_hrel(const unsigned short* __restrict__ h_bf,
                                                 const unsigned short* __restrict__ Wt,
                                                 unsigned short* __restrict__ h_rel) {
    __shared__ unsigned short sA[128][136];
    __shared__ unsigned short sB[128][136];
    const int t = threadIdx.x;
    const int tile = blockIdx.x;
    const int r = blockIdx.y;
    const int base = tile * 128;

    #pragma unroll
    for (int j = 0; j < 8; ++j) {
        int idx = t + j * 256;
        int row = idx >> 4;
        int c8 = (idx & 15) << 3;
        int g = base + row;
        if (g >= NN) g = 0;
        uint4 v = *(const uint4*)(h_bf + (size_t)g * 128 + c8);
        *(uint4*)&sA[row][c8] = v;
    }
    const unsigned short* wp = Wt + (size_t)r * 16384;
    #pragma unroll
    for (int j = 0; j < 8; ++j) {
        int idx = t + j * 256;
        int row = idx >> 4;
        int c8 = (idx & 15) << 3;
        uint4 v = *(const uint4*)(wp + (size_t)row * 128 + c8);
        *(uint4*)&sB[row][c8] = v;
    }
    __syncthreads();

    const int lane = t & 63;
    const int w = t >> 6;
    const int wr = w >> 1, wc = w & 1;
    const int l15 = lane & 15, lhi = lane >> 4;

    f32x4 acc[4][4];
    #pragma unroll
    for (int i = 0; i < 4; ++i)
        #pragma unroll
        for (int j = 0; j < 4; ++j)
            acc[i][j] = (f32x4){0.f, 0.f, 0.f, 0.f};

    #pragma unroll
    for (int kt = 0; kt < 4; ++kt) {
        const int ko = kt * 32 + lhi * 8;
        bf16x8 aF[4], bF[4];
        #pragma unroll
        for (int ms = 0; ms < 4; ++ms) {
            u16x8 raw = *(const u16x8*)&sA[wr * 64 + ms * 16 + l15][ko];
            aF[ms] = __builtin_bit_cast(bf16x8, raw);
        }
        #pragma unroll
        for (int nt = 0; nt < 4; ++nt) {
            u16x8 raw = *(const u16x8*)&sB[wc * 64 + nt * 16 + l15][ko];
            bF[nt] = __builtin_bit_cast(bf16x8, raw);
        }
        #pragma unroll
        for (int ms = 0; ms < 4; ++ms)
            #pragma unroll
            for (int nt = 0; nt < 4; ++nt)
                acc[ms][nt] = __builtin_amdgcn_mfma_f32_16x16x32_bf16(
                    aF[ms], bF[nt], acc[ms][nt], 0, 0, 0);
    }

    #pragma unroll
    for (int ms = 0; ms < 4; ++ms) {
        #pragma unroll
        for (int reg = 0; reg < 4; ++reg) {
            int m = base + wr * 64 + ms * 16 + lhi * 4 + reg;
            if (m < NN) {
                size_t rowp = ((size_t)r * NN + m) * 128;
                #pragma unroll
                for (int nt = 0; nt < 4; ++nt) {
                    int o = wc * 64 + nt * 16 + l15;
                    h_rel[rowp + o] = f2bf(acc[ms][nt][reg]);
                }
            }
        }
    }
}

// ---------------- phase 2: counting sort by dst ---------------------------

// histogram + per-edge rank (coalesced 2B write; atomic return value no
// longer feeds a scattered store)
__global__ __launch_bounds__(256) void hist_rank(const int* __restrict__ dst,
                                                 int* __restrict__ counts,
                                                 unsigned short* __restrict__ rank16) {
    int e = blockIdx.x * 256 + threadIdx.x;
    if (e >= NE) return;
    int old = atomicAdd(&counts[dst[e]], 1);
    rank16[e] = (unsigned short)old;
}

__global__ __launch_bounds__(256) void scanA(const int* __restrict__ counts,
                                             int* __restrict__ blockSums) {
    __shared__ int s[256];
    int t = threadIdx.x;
    int idx = blockIdx.x * 256 + t;
    s[t] = (idx < NN) ? counts[idx] : 0;
    __syncthreads();
    for (int off = 128; off > 0; off >>= 1) {
        if (t < off) s[t] += s[t + off];
        __syncthreads();
    }
    if (t == 0) blockSums[blockIdx.x] = s[0];
}

__global__ __launch_bounds__(256) void scanB(int* __restrict__ blockSums) {
    __shared__ int s[256];
    int t = threadIdx.x;
    int v = (t < 196) ? blockSums[t] : 0;
    s[t] = v;
    __syncthreads();
    for (int off = 1; off < 256; off <<= 1) {
        int x = (t >= off) ? s[t - off] : 0;
        __syncthreads();
        s[t] += x;
        __syncthreads();
    }
    if (t < 196) blockSums[t] = s[t] - v;   // exclusive
}

__global__ __launch_bounds__(256) void scanC(const int* __restrict__ counts,
                                             const int* __restrict__ blockSums,
                                             int* __restrict__ start) {
    __shared__ int s[256];
    int t = threadIdx.x;
    int idx = blockIdx.x * 256 + t;
    int v = (idx < NN) ? counts[idx] : 0;
    s[t] = v;
    __syncthreads();
    for (int off = 1; off < 256; off <<= 1) {
        int x = (t >= off) ? s[t - off] : 0;
        __syncthreads();
        s[t] += x;
        __syncthreads();
    }
    if (idx < NN) start[idx] = blockSums[blockIdx.x] + s[t] - v;
    if (idx == 0) start[NN] = NE;
}

// scatter with precomputed rank: no atomic, short load->store chain
__global__ __launch_bounds__(256) void scatter_norank(const int* __restrict__ src,
                                                      const int* __restrict__ dst,
                                                      const int* __restrict__ rel,
                                                      const float* __restrict__ norm,
                                                      const int* __restrict__ start,
                                                      const unsigned short* __restrict__ rank16,
                                                      uint2* __restrict__ recs) {
    int e = blockIdx.x * 256 + threadIdx.x;
    if (e >= NE) return;
    int pos = start[dst[e]] + (int)rank16[e];
    recs[pos] = make_uint2((unsigned int)src[e] |
                           ((unsigned int)rel[e] << 16),
                           __float_as_uint(norm[e]));
}

// ---------------- phase 3: segmented reduction ----------------------------

__global__ __launch_bounds__(256) void seg_reduce(const int* __restrict__ start,
                                                  const uint2* __restrict__ recs,
                                                  const unsigned int* __restrict__ hb,
                                                  float* __restrict__ out) {
    int gid = blockIdx.x * 256 + threadIdx.x;
    int d = gid >> 6;
    if (d >= NN) return;
    int lane = gid & 63;
    int beg = start[d], end = start[d + 1];
    float a0 = 0.f, a1 = 0.f;
    int i = beg;
    for (; i + 3 < end; i += 4) {
        uint2 rc0 = recs[i];
        uint2 rc1 = recs[i + 1];
        uint2 rc2 = recs[i + 2];
        uint2 rc3 = recs[i + 3];
        unsigned int u0 = hb[(((size_t)(rc0.x >> 16) * NN + (rc0.x & 0xFFFFu)) << 6) + lane];
        unsigned int u1 = hb[(((size_t)(rc1.x >> 16) * NN + (rc1.x & 0xFFFFu)) << 6) + lane];
        unsigned int u2 = hb[(((size_t)(rc2.x >> 16) * NN + (rc2.x & 0xFFFFu)) << 6) + lane];
        unsigned int u3 = hb[(((size_t)(rc3.x >> 16) * NN + (rc3.x & 0xFFFFu)) << 6) + lane];
        float n0 = __uint_as_float(rc0.y), n1 = __uint_as_float(rc1.y);
        float n2 = __uint_as_float(rc2.y), n3 = __uint_as_float(rc3.y);
        a0 += bflo(u0) * n0 + bflo(u1) * n1 + bflo(u2) * n2 + bflo(u3) * n3;
        a1 += bfhi(u0) * n0 + bfhi(u1) * n1 + bfhi(u2) * n2 + bfhi(u3) * n3;
    }
    for (; i < end; ++i) {
        uint2 rc = recs[i];
        unsigned int u = hb[(((size_t)(rc.x >> 16) * NN + (rc.x & 0xFFFFu)) << 6) + lane];
        float nm = __uint_as_float(rc.y);
        a0 += bflo(u) * nm;
        a1 += bfhi(u) * nm;
    }
    *(float2*)(out + (size_t)d * 128 + lane * 2) = make_float2(a0, a1);
}

// ---------------- launch ---------------------------------------------------

extern "C" void kernel_launch(void* const* d_in, const int* in_sizes, int n_in,
                              void* d_out, int out_size, void* d_ws, size_t ws_size,
                              hipStream_t stream) {
    const int* node_ids = (const int*)d_in[0];
    const int* src      = (const int*)d_in[1];
    const int* dst      = (const int*)d_in[2];
    const int* rel      = (const int*)d_in[3];
    const float* norm   = (const float*)d_in[4];
    const float* emb    = (const float*)d_in[5];
    const float* W      = (const float*)d_in[6];
    float* out = (float*)d_out;

    char* ws = (char*)d_ws;
    unsigned short* h_rel = (unsigned short*)(ws);                 // 204,800,000 B
    unsigned short* h_bf  = (unsigned short*)(ws + 204800000);     //  12,800,000 B
    uint2* recs           = (uint2*)(ws + 204800000);              // ALIAS of h_bf
                                                                   // (written only after gemm_hrel)
    unsigned short* Wt    = (unsigned short*)(ws + 217600000);     //     524,288 B
    int* counts           = (int*)(ws + 218124288);                //     200,704 B
    int* start            = (int*)(ws + 218324992);                //     200,708 B
    unsigned short* rank16= (unsigned short*)(ws + 218525696);     //   3,200,000 B
    int* blockSums        = (int*)(ws + 221725696);                //       1,024 B
    // total ~221.7 MB

    hipMemsetAsync(counts, 0, 50176 * sizeof(int), stream);

    prep_h<<<6250, 256, 0, stream>>>(node_ids, emb, h_bf);
    prep_w<<<(NR * HD * OD + 255) / 256, 256, 0, stream>>>(W, Wt);
    hist_rank<<<(NE + 255) / 256, 256, 0, stream>>>(dst, counts, rank16);
    scanA<<<196, 256, 0, stream>>>(counts, blockSums);
    scanB<<<1, 256, 0, stream>>>(blockSums);
    scanC<<<196, 256, 0, stream>>>(counts, blockSums, start);

    gemm_hrel<<<dim3(391, NR), 256, 0, stream>>>(h_bf, Wt, h_rel);

    // recs aliases h_bf — must run after gemm_hrel (stream-serial: ok)
    scatter_norank<<<(NE + 255) / 256, 256, 0, stream>>>(src, dst, rel, norm,
                                                         start, rank16, recs);

    seg_reduce<<<(NN * 64 + 255) / 256, 256, 0, stream>>>(start, recs,
                                                          (const unsigned int*)h_rel,
                                                          out);
}

// Round 7
// 354.527 us; speedup vs baseline: 4.4595x; 1.0234x over previous
//
#include <hip/hip_runtime.h>
#include <hip/hip_bf16.h>

#define NN 50000
#define NE 1600000
#define HD 128
#define OD 128
#define NR 16

typedef __bf16 bf16x8 __attribute__((ext_vector_type(8)));
typedef unsigned short u16x8 __attribute__((ext_vector_type(8)));
typedef float f32x4 __attribute__((ext_vector_type(4)));

__device__ __forceinline__ unsigned short f2bf(float f) {
    union { float f; unsigned int u; } v; v.f = f;
    unsigned int u = v.u;
    u += 0x7FFFu + ((u >> 16) & 1u);   // round-to-nearest-even
    return (unsigned short)(u >> 16);
}
__device__ __forceinline__ float bflo(unsigned int u) {
    union { unsigned int u; float f; } v; v.u = u << 16; return v.f;
}
__device__ __forceinline__ float bfhi(unsigned int u) {
    union { unsigned int u; float f; } v; v.u = u & 0xFFFF0000u; return v.f;
}

// ---------------- phase 1: transform -------------------------------------

// h_bf[n][k] = bf16(emb[node_ids[n]][k])
__global__ __launch_bounds__(256) void prep_h(const int* __restrict__ node_ids,
                                              const float* __restrict__ emb,
                                              unsigned short* __restrict__ h_bf) {
    int gid = blockIdx.x * 256 + threadIdx.x;
    if (gid >= NN * 32) return;
    int row = gid >> 5;
    int c = (gid & 31) << 2;
    int nid = node_ids[row];
    if (nid < 0) nid = 0; if (nid >= NN) nid = NN - 1;
    float4 v = *(const float4*)(emb + (size_t)nid * HD + c);
    ushort4 o;
    o.x = f2bf(v.x); o.y = f2bf(v.y); o.z = f2bf(v.z); o.w = f2bf(v.w);
    *(ushort4*)(h_bf + (size_t)row * HD + c) = o;
}

// Wt[r][o][k] = bf16(W[r][k][o])
__global__ __launch_bounds__(256) void prep_w(const float* __restrict__ W,
                                              unsigned short* __restrict__ Wt) {
    int gid = blockIdx.x * 256 + threadIdx.x;
    if (gid >= NR * HD * OD) return;
    int r = gid >> 14;
    int idx = gid & 16383;
    int k = idx >> 7;
    int o = idx & 127;
    Wt[(size_t)r * 16384 + (size_t)o * 128 + k] = f2bf(W[gid]);
}

// GEMM: h_rel[r][n][o] = sum_k h_bf[n][k] * W[r][k][o], stored bf16.
// Grid (391, 4): block stages its 128-node A-tile ONCE, then loops 4 rels
// (stage B, 64 MFMAs, store) — 4x less A staging + 4x fewer blocks.
__global__ __launch_bounds__(256) void gemm_hrel(const unsigned short* __restrict__ h_bf,
                                                 const unsigned short* __restrict__ Wt,
                                                 unsigned short* __restrict__ h_rel) {
    __shared__ unsigned short sA[128][136];
    __shared__ unsigned short sB[128][136];
    const int t = threadIdx.x;
    const int base = blockIdx.x * 128;
    const int rg = blockIdx.y;

    #pragma unroll
    for (int j = 0; j < 8; ++j) {
        int idx = t + j * 256;
        int row = idx >> 4;
        int c8 = (idx & 15) << 3;
        int g = base + row;
        if (g >= NN) g = 0;
        uint4 v = *(const uint4*)(h_bf + (size_t)g * 128 + c8);
        *(uint4*)&sA[row][c8] = v;
    }

    const int lane = t & 63;
    const int w = t >> 6;
    const int wr = w >> 1, wc = w & 1;
    const int l15 = lane & 15, lhi = lane >> 4;

    for (int rr = 0; rr < 4; ++rr) {
        const int r = rg * 4 + rr;
        if (rr > 0) __syncthreads();          // prev iter done reading sB
        const unsigned short* wp = Wt + ((size_t)r << 14);
        #pragma unroll
        for (int j = 0; j < 8; ++j) {
            int idx = t + j * 256;
            int row = idx >> 4;
            int c8 = (idx & 15) << 3;
            uint4 v = *(const uint4*)(wp + (size_t)row * 128 + c8);
            *(uint4*)&sB[row][c8] = v;
        }
        __syncthreads();

        f32x4 acc[4][4];
        #pragma unroll
        for (int i = 0; i < 4; ++i)
            #pragma unroll
            for (int j = 0; j < 4; ++j)
                acc[i][j] = (f32x4){0.f, 0.f, 0.f, 0.f};

        #pragma unroll
        for (int kt = 0; kt < 4; ++kt) {
            const int ko = kt * 32 + lhi * 8;
            bf16x8 aF[4], bF[4];
            #pragma unroll
            for (int ms = 0; ms < 4; ++ms) {
                u16x8 raw = *(const u16x8*)&sA[wr * 64 + ms * 16 + l15][ko];
                aF[ms] = __builtin_bit_cast(bf16x8, raw);
            }
            #pragma unroll
            for (int nt = 0; nt < 4; ++nt) {
                u16x8 raw = *(const u16x8*)&sB[wc * 64 + nt * 16 + l15][ko];
                bF[nt] = __builtin_bit_cast(bf16x8, raw);
            }
            #pragma unroll
            for (int ms = 0; ms < 4; ++ms)
                #pragma unroll
                for (int nt = 0; nt < 4; ++nt)
                    acc[ms][nt] = __builtin_amdgcn_mfma_f32_16x16x32_bf16(
                        aF[ms], bF[nt], acc[ms][nt], 0, 0, 0);
        }

        #pragma unroll
        for (int ms = 0; ms < 4; ++ms) {
            #pragma unroll
            for (int reg = 0; reg < 4; ++reg) {
                int m = base + wr * 64 + ms * 16 + lhi * 4 + reg;
                if (m < NN) {
                    size_t rowp = ((size_t)r * NN + m) * 128;
                    #pragma unroll
                    for (int nt = 0; nt < 4; ++nt) {
                        int o = wc * 64 + nt * 16 + l15;
                        h_rel[rowp + o] = f2bf(acc[ms][nt][reg]);
                    }
                }
            }
        }
    }
}

// ---------------- phase 2: counting sort by dst ---------------------------

__global__ __launch_bounds__(256) void hist_rank(const int* __restrict__ dst,
                                                 int* __restrict__ counts,
                                                 unsigned short* __restrict__ rank16) {
    int e = blockIdx.x * 256 + threadIdx.x;
    if (e >= NE) return;
    int old = atomicAdd(&counts[dst[e]], 1);
    rank16[e] = (unsigned short)old;
}

__global__ __launch_bounds__(256) void scanA(const int* __restrict__ counts,
                                             int* __restrict__ blockSums) {
    __shared__ int s[256];
    int t = threadIdx.x;
    int idx = blockIdx.x * 256 + t;
    s[t] = (idx < NN) ? counts[idx] : 0;
    __syncthreads();
    for (int off = 128; off > 0; off >>= 1) {
        if (t < off) s[t] += s[t + off];
        __syncthreads();
    }
    if (t == 0) blockSums[blockIdx.x] = s[0];
}

__global__ __launch_bounds__(256) void scanB(int* __restrict__ blockSums) {
    __shared__ int s[256];
    int t = threadIdx.x;
    int v = (t < 196) ? blockSums[t] : 0;
    s[t] = v;
    __syncthreads();
    for (int off = 1; off < 256; off <<= 1) {
        int x = (t >= off) ? s[t - off] : 0;
        __syncthreads();
        s[t] += x;
        __syncthreads();
    }
    if (t < 196) blockSums[t] = s[t] - v;   // exclusive
}

__global__ __launch_bounds__(256) void scanC(const int* __restrict__ counts,
                                             const int* __restrict__ blockSums,
                                             int* __restrict__ start) {
    __shared__ int s[256];
    int t = threadIdx.x;
    int idx = blockIdx.x * 256 + t;
    int v = (idx < NN) ? counts[idx] : 0;
    s[t] = v;
    __syncthreads();
    for (int off = 1; off < 256; off <<= 1) {
        int x = (t >= off) ? s[t - off] : 0;
        __syncthreads();
        s[t] += x;
        __syncthreads();
    }
    if (idx < NN) start[idx] = blockSums[blockIdx.x] + s[t] - v;
    if (idx == 0) start[NN] = NE;
}

// scatter: rec.x = rel*NN+src (the seg_reduce gather index, precomputed here)
__global__ __launch_bounds__(256) void scatter_norank(const int* __restrict__ src,
                                                      const int* __restrict__ dst,
                                                      const int* __restrict__ rel,
                                                      const float* __restrict__ norm,
                                                      const int* __restrict__ start,
                                                      const unsigned short* __restrict__ rank16,
                                                      uint2* __restrict__ recs) {
    int e = blockIdx.x * 256 + threadIdx.x;
    if (e >= NE) return;
    int pos = start[dst[e]] + (int)rank16[e];
    recs[pos] = make_uint2((unsigned int)(rel[e] * NN + src[e]),
                           __float_as_uint(norm[e]));
}

// ---------------- phase 3: segmented reduction ----------------------------
// one wave per dst node (wave-uniform d); lane owns 2 output cols.
// unroll-8 with uint4 rec loads (alignment-peeled) -> 8 gathers in flight;
// gather index precomputed in rec.x (addr = one v_lshl_add).
__global__ __launch_bounds__(256) void seg_reduce(const int* __restrict__ start,
                                                  const uint2* __restrict__ recs,
                                                  const unsigned int* __restrict__ hb,
                                                  float* __restrict__ out) {
    int d = blockIdx.x * 4 + (threadIdx.x >> 6);   // wave-uniform
    if (d >= NN) return;
    int lane = threadIdx.x & 63;
    int beg = start[d], end = start[d + 1];
    float a0 = 0.f, a1 = 0.f;
    int i = beg;
    if ((i & 1) && i < end) {                      // align to 16B for uint4
        uint2 rc = recs[i];
        unsigned int u = hb[rc.x * 64u + lane];
        float nm = __uint_as_float(rc.y);
        a0 += bflo(u) * nm;
        a1 += bfhi(u) * nm;
        ++i;
    }
    for (; i + 7 < end; i += 8) {
        uint4 p0 = *(const uint4*)&recs[i];
        uint4 p1 = *(const uint4*)&recs[i + 2];
        uint4 p2 = *(const uint4*)&recs[i + 4];
        uint4 p3 = *(const uint4*)&recs[i + 6];
        unsigned int u0 = hb[p0.x * 64u + lane];
        unsigned int u1 = hb[p0.z * 64u + lane];
        unsigned int u2 = hb[p1.x * 64u + lane];
        unsigned int u3 = hb[p1.z * 64u + lane];
        unsigned int u4 = hb[p2.x * 64u + lane];
        unsigned int u5 = hb[p2.z * 64u + lane];
        unsigned int u6 = hb[p3.x * 64u + lane];
        unsigned int u7 = hb[p3.z * 64u + lane];
        float n0 = __uint_as_float(p0.y), n1 = __uint_as_float(p0.w);
        float n2 = __uint_as_float(p1.y), n3 = __uint_as_float(p1.w);
        float n4 = __uint_as_float(p2.y), n5 = __uint_as_float(p2.w);
        float n6 = __uint_as_float(p3.y), n7 = __uint_as_float(p3.w);
        a0 += bflo(u0) * n0 + bflo(u1) * n1 + bflo(u2) * n2 + bflo(u3) * n3;
        a1 += bfhi(u0) * n0 + bfhi(u1) * n1 + bfhi(u2) * n2 + bfhi(u3) * n3;
        a0 += bflo(u4) * n4 + bflo(u5) * n5 + bflo(u6) * n6 + bflo(u7) * n7;
        a1 += bfhi(u4) * n4 + bfhi(u5) * n5 + bfhi(u6) * n6 + bfhi(u7) * n7;
    }
    for (; i < end; ++i) {
        uint2 rc = recs[i];
        unsigned int u = hb[rc.x * 64u + lane];
        float nm = __uint_as_float(rc.y);
        a0 += bflo(u) * nm;
        a1 += bfhi(u) * nm;
    }
    *(float2*)(out + (size_t)d * 128 + lane * 2) = make_float2(a0, a1);
}

// ---------------- launch ---------------------------------------------------

extern "C" void kernel_launch(void* const* d_in, const int* in_sizes, int n_in,
                              void* d_out, int out_size, void* d_ws, size_t ws_size,
                              hipStream_t stream) {
    const int* node_ids = (const int*)d_in[0];
    const int* src      = (const int*)d_in[1];
    const int* dst      = (const int*)d_in[2];
    const int* rel      = (const int*)d_in[3];
    const float* norm   = (const float*)d_in[4];
    const float* emb    = (const float*)d_in[5];
    const float* W      = (const float*)d_in[6];
    float* out = (float*)d_out;

    char* ws = (char*)d_ws;
    unsigned short* h_rel = (unsigned short*)(ws);                 // 204,800,000 B
    unsigned short* h_bf  = (unsigned short*)(ws + 204800000);     //  12,800,000 B
    uint2* recs           = (uint2*)(ws + 204800000);              // ALIAS of h_bf
                                                                   // (written only after gemm_hrel)
    unsigned short* Wt    = (unsigned short*)(ws + 217600000);     //     524,288 B
    int* counts           = (int*)(ws + 218124288);                //     200,704 B
    int* start            = (int*)(ws + 218324992);                //     200,708 B
    unsigned short* rank16= (unsigned short*)(ws + 218525696);     //   3,200,000 B
    int* blockSums        = (int*)(ws + 221725696);                //       1,024 B

    hipMemsetAsync(counts, 0, 50176 * sizeof(int), stream);

    prep_h<<<6250, 256, 0, stream>>>(node_ids, emb, h_bf);
    prep_w<<<(NR * HD * OD + 255) / 256, 256, 0, stream>>>(W, Wt);
    hist_rank<<<(NE + 255) / 256, 256, 0, stream>>>(dst, counts, rank16);
    scanA<<<196, 256, 0, stream>>>(counts, blockSums);
    scanB<<<1, 256, 0, stream>>>(blockSums);
    scanC<<<196, 256, 0, stream>>>(counts, blockSums, start);

    gemm_hrel<<<dim3(391, 4), 256, 0, stream>>>(h_bf, Wt, h_rel);

    // recs aliases h_bf — must run after gemm_hrel (stream-serial: ok)
    scatter_norank<<<(NE + 255) / 256, 256, 0, stream>>>(src, dst, rel, norm,
                                                         start, rank16, recs);

    seg_reduce<<<12500, 256, 0, stream>>>(start, recs,
                                          (const unsigned int*)h_rel, out);
}

// Round 8
// 349.527 us; speedup vs baseline: 4.5233x; 1.0143x over previous
//
#include <hip/hip_runtime.h>
#include <hip/hip_bf16.h>

#define NN 50000
#define NE 1600000
#define HD 128
#define OD 128
#define NR 16
#define NNP 50176                // 196*256 padded counter plane
#define PREPH_BLKS 6250
#define PREPW_BLKS 1024
#define HIST_BLKS 1563           // NE/4/256 = 1562.5 -> 1563

typedef __bf16 bf16x8 __attribute__((ext_vector_type(8)));
typedef unsigned short u16x8 __attribute__((ext_vector_type(8)));
typedef float f32x4 __attribute__((ext_vector_type(4)));

__device__ __forceinline__ unsigned short f2bf(float f) {
    union { float f; unsigned int u; } v; v.f = f;
    unsigned int u = v.u;
    u += 0x7FFFu + ((u >> 16) & 1u);   // round-to-nearest-even
    return (unsigned short)(u >> 16);
}
__device__ __forceinline__ float bflo(unsigned int u) {
    union { unsigned int u; float f; } v; v.u = u << 16; return v.f;
}
__device__ __forceinline__ float bfhi(unsigned int u) {
    union { unsigned int u; float f; } v; v.u = u & 0xFFFF0000u; return v.f;
}

// ---------------- fused prep: h cast + W transpose + sharded histogram ----
__global__ __launch_bounds__(256) void prep_fused(const int* __restrict__ node_ids,
                                                  const float* __restrict__ emb,
                                                  unsigned short* __restrict__ h_bf,
                                                  const float* __restrict__ W,
                                                  unsigned short* __restrict__ Wt,
                                                  const int* __restrict__ dst,
                                                  int* __restrict__ counts4,
                                                  unsigned short* __restrict__ rank16) {
    const int b = blockIdx.x;
    const int t = threadIdx.x;
    if (b < PREPH_BLKS) {
        // h_bf[n][k] = bf16(emb[node_ids[n]][k])
        int gid = b * 256 + t;
        int row = gid >> 5;
        int c = (gid & 31) << 2;
        int nid = node_ids[row];
        if (nid < 0) nid = 0; if (nid >= NN) nid = NN - 1;
        float4 v = *(const float4*)(emb + (size_t)nid * HD + c);
        ushort4 o;
        o.x = f2bf(v.x); o.y = f2bf(v.y); o.z = f2bf(v.z); o.w = f2bf(v.w);
        *(ushort4*)(h_bf + (size_t)row * HD + c) = o;
    } else if (b < PREPH_BLKS + PREPW_BLKS) {
        // Wt[r][o][k] = bf16(W[r][k][o])
        int gid = (b - PREPH_BLKS) * 256 + t;
        int r = gid >> 14;
        int idx = gid & 16383;
        int k = idx >> 7;
        int o = idx & 127;
        Wt[(size_t)r * 16384 + (size_t)o * 128 + k] = f2bf(W[gid]);
    } else {
        // sharded histogram: 4 edges/thread, plane = e & 3
        int t4 = ((b - PREPH_BLKS - PREPW_BLKS) * 256 + t) * 4;
        if (t4 >= NE) return;
        int4 dv = *(const int4*)(dst + t4);
        int r0 = atomicAdd(&counts4[dv.x], 1);
        int r1 = atomicAdd(&counts4[NNP + dv.y], 1);
        int r2 = atomicAdd(&counts4[2 * NNP + dv.z], 1);
        int r3 = atomicAdd(&counts4[3 * NNP + dv.w], 1);
        ushort4 rk;
        rk.x = (unsigned short)r0; rk.y = (unsigned short)r1;
        rk.z = (unsigned short)r2; rk.w = (unsigned short)r3;
        *(ushort4*)(rank16 + t4) = rk;
    }
}

// ---------------- phase 1: transform (unchanged from round 7) -------------
__global__ __launch_bounds__(256) void gemm_hrel(const unsigned short* __restrict__ h_bf,
                                                 const unsigned short* __restrict__ Wt,
                                                 unsigned short* __restrict__ h_rel) {
    __shared__ unsigned short sA[128][136];
    __shared__ unsigned short sB[128][136];
    const int t = threadIdx.x;
    const int base = blockIdx.x * 128;
    const int rg = blockIdx.y;

    #pragma unroll
    for (int j = 0; j < 8; ++j) {
        int idx = t + j * 256;
        int row = idx >> 4;
        int c8 = (idx & 15) << 3;
        int g = base + row;
        if (g >= NN) g = 0;
        uint4 v = *(const uint4*)(h_bf + (size_t)g * 128 + c8);
        *(uint4*)&sA[row][c8] = v;
    }

    const int lane = t & 63;
    const int w = t >> 6;
    const int wr = w >> 1, wc = w & 1;
    const int l15 = lane & 15, lhi = lane >> 4;

    for (int rr = 0; rr < 4; ++rr) {
        const int r = rg * 4 + rr;
        if (rr > 0) __syncthreads();
        const unsigned short* wp = Wt + ((size_t)r << 14);
        #pragma unroll
        for (int j = 0; j < 8; ++j) {
            int idx = t + j * 256;
            int row = idx >> 4;
            int c8 = (idx & 15) << 3;
            uint4 v = *(const uint4*)(wp + (size_t)row * 128 + c8);
            *(uint4*)&sB[row][c8] = v;
        }
        __syncthreads();

        f32x4 acc[4][4];
        #pragma unroll
        for (int i = 0; i < 4; ++i)
            #pragma unroll
            for (int j = 0; j < 4; ++j)
                acc[i][j] = (f32x4){0.f, 0.f, 0.f, 0.f};

        #pragma unroll
        for (int kt = 0; kt < 4; ++kt) {
            const int ko = kt * 32 + lhi * 8;
            bf16x8 aF[4], bF[4];
            #pragma unroll
            for (int ms = 0; ms < 4; ++ms) {
                u16x8 raw = *(const u16x8*)&sA[wr * 64 + ms * 16 + l15][ko];
                aF[ms] = __builtin_bit_cast(bf16x8, raw);
            }
            #pragma unroll
            for (int nt = 0; nt < 4; ++nt) {
                u16x8 raw = *(const u16x8*)&sB[wc * 64 + nt * 16 + l15][ko];
                bF[nt] = __builtin_bit_cast(bf16x8, raw);
            }
            #pragma unroll
            for (int ms = 0; ms < 4; ++ms)
                #pragma unroll
                for (int nt = 0; nt < 4; ++nt)
                    acc[ms][nt] = __builtin_amdgcn_mfma_f32_16x16x32_bf16(
                        aF[ms], bF[nt], acc[ms][nt], 0, 0, 0);
        }

        #pragma unroll
        for (int ms = 0; ms < 4; ++ms) {
            #pragma unroll
            for (int reg = 0; reg < 4; ++reg) {
                int m = base + wr * 64 + ms * 16 + lhi * 4 + reg;
                if (m < NN) {
                    size_t rowp = ((size_t)r * NN + m) * 128;
                    #pragma unroll
                    for (int nt = 0; nt < 4; ++nt) {
                        int o = wc * 64 + nt * 16 + l15;
                        h_rel[rowp + o] = f2bf(acc[ms][nt][reg]);
                    }
                }
            }
        }
    }
}

// ---------------- scans ----------------------------------------------------

__global__ __launch_bounds__(256) void scanA(const int* __restrict__ counts4,
                                             int* __restrict__ blockSums) {
    __shared__ int s[256];
    int t = threadIdx.x;
    int idx = blockIdx.x * 256 + t;
    s[t] = counts4[idx] + counts4[NNP + idx] + counts4[2 * NNP + idx]
         + counts4[3 * NNP + idx];
    __syncthreads();
    for (int off = 128; off > 0; off >>= 1) {
        if (t < off) s[t] += s[t + off];
        __syncthreads();
    }
    if (t == 0) blockSums[blockIdx.x] = s[0];
}

__global__ __launch_bounds__(256) void scanB(int* __restrict__ blockSums) {
    __shared__ int s[256];
    int t = threadIdx.x;
    int v = (t < 196) ? blockSums[t] : 0;
    s[t] = v;
    __syncthreads();
    for (int off = 1; off < 256; off <<= 1) {
        int x = (t >= off) ? s[t - off] : 0;
        __syncthreads();
        s[t] += x;
        __syncthreads();
    }
    if (t < 196) blockSums[t] = s[t] - v;   // exclusive
}

// scan + fold shard prefixes: plane p := start[d] + sum of planes < p.
// plane 0 becomes the plain start[] array (sentinel at idx>=NN = NE).
__global__ __launch_bounds__(256) void scanC(int* __restrict__ counts4,
                                             const int* __restrict__ blockSums) {
    __shared__ int s[256];
    int t = threadIdx.x;
    int idx = blockIdx.x * 256 + t;
    int c0 = counts4[idx], c1 = counts4[NNP + idx];
    int c2 = counts4[2 * NNP + idx], c3 = counts4[3 * NNP + idx];
    int v = c0 + c1 + c2 + c3;
    s[t] = v;
    __syncthreads();
    for (int off = 1; off < 256; off <<= 1) {
        int x = (t >= off) ? s[t - off] : 0;
        __syncthreads();
        s[t] += x;
        __syncthreads();
    }
    int st = blockSums[blockIdx.x] + s[t] - v;
    counts4[idx] = st;
    counts4[NNP + idx] = st + c0;
    counts4[2 * NNP + idx] = st + c0 + c1;
    counts4[3 * NNP + idx] = st + c0 + c1 + c2;
}

// scatter: pos = startS[e&3][dst] + rank; rec.x = rel*NN+src (gather index)
__global__ __launch_bounds__(256) void scatter_norank(const int* __restrict__ src,
                                                      const int* __restrict__ dst,
                                                      const int* __restrict__ rel,
                                                      const float* __restrict__ norm,
                                                      const int* __restrict__ startS,
                                                      const unsigned short* __restrict__ rank16,
                                                      uint2* __restrict__ recs) {
    int e = blockIdx.x * 256 + threadIdx.x;
    if (e >= NE) return;
    int pos = startS[(e & 3) * NNP + dst[e]] + (int)rank16[e];
    recs[pos] = make_uint2((unsigned int)(rel[e] * NN + src[e]),
                           __float_as_uint(norm[e]));
}

// ---------------- phase 3: segmented reduction (round-7 structure) --------
__global__ __launch_bounds__(256) void seg_reduce(const int* __restrict__ start,
                                                  const uint2* __restrict__ recs,
                                                  const unsigned int* __restrict__ hb,
                                                  float* __restrict__ out) {
    int d = blockIdx.x * 4 + (threadIdx.x >> 6);   // wave-uniform
    if (d >= NN) return;
    int lane = threadIdx.x & 63;
    int beg = start[d], end = start[d + 1];
    float a0 = 0.f, a1 = 0.f;
    int i = beg;
    if ((i & 1) && i < end) {
        uint2 rc = recs[i];
        unsigned int u = hb[rc.x * 64u + lane];
        float nm = __uint_as_float(rc.y);
        a0 += bflo(u) * nm;
        a1 += bfhi(u) * nm;
        ++i;
    }
    for (; i + 7 < end; i += 8) {
        uint4 p0 = *(const uint4*)&recs[i];
        uint4 p1 = *(const uint4*)&recs[i + 2];
        uint4 p2 = *(const uint4*)&recs[i + 4];
        uint4 p3 = *(const uint4*)&recs[i + 6];
        unsigned int u0 = hb[p0.x * 64u + lane];
        unsigned int u1 = hb[p0.z * 64u + lane];
        unsigned int u2 = hb[p1.x * 64u + lane];
        unsigned int u3 = hb[p1.z * 64u + lane];
        unsigned int u4 = hb[p2.x * 64u + lane];
        unsigned int u5 = hb[p2.z * 64u + lane];
        unsigned int u6 = hb[p3.x * 64u + lane];
        unsigned int u7 = hb[p3.z * 64u + lane];
        float n0 = __uint_as_float(p0.y), n1 = __uint_as_float(p0.w);
        float n2 = __uint_as_float(p1.y), n3 = __uint_as_float(p1.w);
        float n4 = __uint_as_float(p2.y), n5 = __uint_as_float(p2.w);
        float n6 = __uint_as_float(p3.y), n7 = __uint_as_float(p3.w);
        a0 += bflo(u0) * n0 + bflo(u1) * n1 + bflo(u2) * n2 + bflo(u3) * n3;
        a1 += bfhi(u0) * n0 + bfhi(u1) * n1 + bfhi(u2) * n2 + bfhi(u3) * n3;
        a0 += bflo(u4) * n4 + bflo(u5) * n5 + bflo(u6) * n6 + bflo(u7) * n7;
        a1 += bfhi(u4) * n4 + bfhi(u5) * n5 + bfhi(u6) * n6 + bfhi(u7) * n7;
    }
    for (; i < end; ++i) {
        uint2 rc = recs[i];
        unsigned int u = hb[rc.x * 64u + lane];
        float nm = __uint_as_float(rc.y);
        a0 += bflo(u) * nm;
        a1 += bfhi(u) * nm;
    }
    *(float2*)(out + (size_t)d * 128 + lane * 2) = make_float2(a0, a1);
}

// ---------------- launch ---------------------------------------------------

extern "C" void kernel_launch(void* const* d_in, const int* in_sizes, int n_in,
                              void* d_out, int out_size, void* d_ws, size_t ws_size,
                              hipStream_t stream) {
    const int* node_ids = (const int*)d_in[0];
    const int* src      = (const int*)d_in[1];
    const int* dst      = (const int*)d_in[2];
    const int* rel      = (const int*)d_in[3];
    const float* norm   = (const float*)d_in[4];
    const float* emb    = (const float*)d_in[5];
    const float* W      = (const float*)d_in[6];
    float* out = (float*)d_out;

    char* ws = (char*)d_ws;
    unsigned short* h_rel = (unsigned short*)(ws);                 // 204,800,000 B
    unsigned short* h_bf  = (unsigned short*)(ws + 204800000);     //  12,800,000 B
    uint2* recs           = (uint2*)(ws + 204800000);              // ALIAS of h_bf
                                                                   // (written only after gemm_hrel)
    unsigned short* Wt    = (unsigned short*)(ws + 217600000);     //     524,288 B
    int* counts4          = (int*)(ws + 218124288);                //     802,816 B (4 planes)
    unsigned short* rank16= (unsigned short*)(ws + 218927104);     //   3,200,000 B
    int* blockSums        = (int*)(ws + 222127104);                //       1,024 B
    // total ~222.1 MB

    hipMemsetAsync(counts4, 0, 4 * NNP * sizeof(int), stream);

    prep_fused<<<PREPH_BLKS + PREPW_BLKS + HIST_BLKS, 256, 0, stream>>>(
        node_ids, emb, h_bf, W, Wt, dst, counts4, rank16);
    scanA<<<196, 256, 0, stream>>>(counts4, blockSums);
    scanB<<<1, 256, 0, stream>>>(blockSums);
    scanC<<<196, 256, 0, stream>>>(counts4, blockSums);

    gemm_hrel<<<dim3(391, 4), 256, 0, stream>>>(h_bf, Wt, h_rel);

    // recs aliases h_bf — must run after gemm_hrel (stream-serial: ok)
    scatter_norank<<<(NE + 255) / 256, 256, 0, stream>>>(src, dst, rel, norm,
                                                         counts4, rank16, recs);

    // start[] = counts4 plane 0 (scanC folded shard prefixes; sentinel at NN)
    seg_reduce<<<12500, 256, 0, stream>>>(counts4, recs,
                                          (const unsigned int*)h_rel, out);
}

// Round 9
// 337.722 us; speedup vs baseline: 4.6814x; 1.0350x over previous
//
#include <hip/hip_runtime.h>
#include <hip/hip_bf16.h>

#define NN 50000
#define NE 1600000
#define HD 128
#define OD 128
#define NR 16
#define NNP 50176                // 196*256 padded counter plane
#define HIST_BLKS 391            // NE/16/256 = 390.625 -> 391 (16 edges/thread)
#define PREPH_BLKS 6250
#define PREPW_BLKS 1024

typedef __bf16 bf16x8 __attribute__((ext_vector_type(8)));
typedef unsigned short u16x8 __attribute__((ext_vector_type(8)));
typedef float f32x4 __attribute__((ext_vector_type(4)));

__device__ __forceinline__ unsigned short f2bf(float f) {
    union { float f; unsigned int u; } v; v.f = f;
    unsigned int u = v.u;
    u += 0x7FFFu + ((u >> 16) & 1u);   // round-to-nearest-even
    return (unsigned short)(u >> 16);
}
__device__ __forceinline__ float bflo(unsigned int u) {
    union { unsigned int u; float f; } v; v.u = u << 16; return v.f;
}
__device__ __forceinline__ float bfhi(unsigned int u) {
    union { unsigned int u; float f; } v; v.u = u & 0xFFFF0000u; return v.f;
}

// ---------------- fused prep: sharded hist (first!) + h cast + W transpose
__global__ __launch_bounds__(256) void prep_fused(const int* __restrict__ node_ids,
                                                  const float* __restrict__ emb,
                                                  unsigned short* __restrict__ h_bf,
                                                  const float* __restrict__ W,
                                                  unsigned short* __restrict__ Wt,
                                                  const int* __restrict__ dst,
                                                  int* __restrict__ counts4,
                                                  unsigned short* __restrict__ rank16) {
    const int b = blockIdx.x;
    const int t = threadIdx.x;
    if (b < HIST_BLKS) {
        // sharded histogram: 16 edges/thread, plane = e & 3, 16 atomics in flight
        int t16 = (b * 256 + t) * 16;
        if (t16 >= NE) return;               // NE % 16 == 0 -> full groups only
        int4 d0 = *(const int4*)(dst + t16);
        int4 d1 = *(const int4*)(dst + t16 + 4);
        int4 d2 = *(const int4*)(dst + t16 + 8);
        int4 d3 = *(const int4*)(dst + t16 + 12);
        int r0  = atomicAdd(&counts4[d0.x], 1);
        int r1  = atomicAdd(&counts4[NNP + d0.y], 1);
        int r2  = atomicAdd(&counts4[2 * NNP + d0.z], 1);
        int r3  = atomicAdd(&counts4[3 * NNP + d0.w], 1);
        int r4  = atomicAdd(&counts4[d1.x], 1);
        int r5  = atomicAdd(&counts4[NNP + d1.y], 1);
        int r6  = atomicAdd(&counts4[2 * NNP + d1.z], 1);
        int r7  = atomicAdd(&counts4[3 * NNP + d1.w], 1);
        int r8  = atomicAdd(&counts4[d2.x], 1);
        int r9  = atomicAdd(&counts4[NNP + d2.y], 1);
        int r10 = atomicAdd(&counts4[2 * NNP + d2.z], 1);
        int r11 = atomicAdd(&counts4[3 * NNP + d2.w], 1);
        int r12 = atomicAdd(&counts4[d3.x], 1);
        int r13 = atomicAdd(&counts4[NNP + d3.y], 1);
        int r14 = atomicAdd(&counts4[2 * NNP + d3.z], 1);
        int r15 = atomicAdd(&counts4[3 * NNP + d3.w], 1);
        uint4 pa, pb;
        pa.x = (unsigned int)(r0  & 0xFFFF) | ((unsigned int)r1  << 16);
        pa.y = (unsigned int)(r2  & 0xFFFF) | ((unsigned int)r3  << 16);
        pa.z = (unsigned int)(r4  & 0xFFFF) | ((unsigned int)r5  << 16);
        pa.w = (unsigned int)(r6  & 0xFFFF) | ((unsigned int)r7  << 16);
        pb.x = (unsigned int)(r8  & 0xFFFF) | ((unsigned int)r9  << 16);
        pb.y = (unsigned int)(r10 & 0xFFFF) | ((unsigned int)r11 << 16);
        pb.z = (unsigned int)(r12 & 0xFFFF) | ((unsigned int)r13 << 16);
        pb.w = (unsigned int)(r14 & 0xFFFF) | ((unsigned int)r15 << 16);
        *(uint4*)(rank16 + t16) = pa;
        *(uint4*)(rank16 + t16 + 8) = pb;
    } else if (b < HIST_BLKS + PREPH_BLKS) {
        // h_bf[n][k] = bf16(emb[node_ids[n]][k])
        int gid = (b - HIST_BLKS) * 256 + t;
        int row = gid >> 5;
        int c = (gid & 31) << 2;
        int nid = node_ids[row];
        if (nid < 0) nid = 0; if (nid >= NN) nid = NN - 1;
        float4 v = *(const float4*)(emb + (size_t)nid * HD + c);
        ushort4 o;
        o.x = f2bf(v.x); o.y = f2bf(v.y); o.z = f2bf(v.z); o.w = f2bf(v.w);
        *(ushort4*)(h_bf + (size_t)row * HD + c) = o;
    } else {
        // Wt[r][o][k] = bf16(W[r][k][o])
        int gid = (b - HIST_BLKS - PREPH_BLKS) * 256 + t;
        int r = gid >> 14;
        int idx = gid & 16383;
        int k = idx >> 7;
        int o = idx & 127;
        Wt[(size_t)r * 16384 + (size_t)o * 128 + k] = f2bf(W[gid]);
    }
}

// ---------------- phase 1: transform (unchanged) --------------------------
__global__ __launch_bounds__(256) void gemm_hrel(const unsigned short* __restrict__ h_bf,
                                                 const unsigned short* __restrict__ Wt,
                                                 unsigned short* __restrict__ h_rel) {
    __shared__ unsigned short sA[128][136];
    __shared__ unsigned short sB[128][136];
    const int t = threadIdx.x;
    const int base = blockIdx.x * 128;
    const int rg = blockIdx.y;

    #pragma unroll
    for (int j = 0; j < 8; ++j) {
        int idx = t + j * 256;
        int row = idx >> 4;
        int c8 = (idx & 15) << 3;
        int g = base + row;
        if (g >= NN) g = 0;
        uint4 v = *(const uint4*)(h_bf + (size_t)g * 128 + c8);
        *(uint4*)&sA[row][c8] = v;
    }

    const int lane = t & 63;
    const int w = t >> 6;
    const int wr = w >> 1, wc = w & 1;
    const int l15 = lane & 15, lhi = lane >> 4;

    for (int rr = 0; rr < 4; ++rr) {
        const int r = rg * 4 + rr;
        if (rr > 0) __syncthreads();
        const unsigned short* wp = Wt + ((size_t)r << 14);
        #pragma unroll
        for (int j = 0; j < 8; ++j) {
            int idx = t + j * 256;
            int row = idx >> 4;
            int c8 = (idx & 15) << 3;
            uint4 v = *(const uint4*)(wp + (size_t)row * 128 + c8);
            *(uint4*)&sB[row][c8] = v;
        }
        __syncthreads();

        f32x4 acc[4][4];
        #pragma unroll
        for (int i = 0; i < 4; ++i)
            #pragma unroll
            for (int j = 0; j < 4; ++j)
                acc[i][j] = (f32x4){0.f, 0.f, 0.f, 0.f};

        #pragma unroll
        for (int kt = 0; kt < 4; ++kt) {
            const int ko = kt * 32 + lhi * 8;
            bf16x8 aF[4], bF[4];
            #pragma unroll
            for (int ms = 0; ms < 4; ++ms) {
                u16x8 raw = *(const u16x8*)&sA[wr * 64 + ms * 16 + l15][ko];
                aF[ms] = __builtin_bit_cast(bf16x8, raw);
            }
            #pragma unroll
            for (int nt = 0; nt < 4; ++nt) {
                u16x8 raw = *(const u16x8*)&sB[wc * 64 + nt * 16 + l15][ko];
                bF[nt] = __builtin_bit_cast(bf16x8, raw);
            }
            #pragma unroll
            for (int ms = 0; ms < 4; ++ms)
                #pragma unroll
                for (int nt = 0; nt < 4; ++nt)
                    acc[ms][nt] = __builtin_amdgcn_mfma_f32_16x16x32_bf16(
                        aF[ms], bF[nt], acc[ms][nt], 0, 0, 0);
        }

        #pragma unroll
        for (int ms = 0; ms < 4; ++ms) {
            #pragma unroll
            for (int reg = 0; reg < 4; ++reg) {
                int m = base + wr * 64 + ms * 16 + lhi * 4 + reg;
                if (m < NN) {
                    size_t rowp = ((size_t)r * NN + m) * 128;
                    #pragma unroll
                    for (int nt = 0; nt < 4; ++nt) {
                        int o = wc * 64 + nt * 16 + l15;
                        h_rel[rowp + o] = f2bf(acc[ms][nt][reg]);
                    }
                }
            }
        }
    }
}

// ---------------- scans (unchanged) ----------------------------------------

__global__ __launch_bounds__(256) void scanA(const int* __restrict__ counts4,
                                             int* __restrict__ blockSums) {
    __shared__ int s[256];
    int t = threadIdx.x;
    int idx = blockIdx.x * 256 + t;
    s[t] = counts4[idx] + counts4[NNP + idx] + counts4[2 * NNP + idx]
         + counts4[3 * NNP + idx];
    __syncthreads();
    for (int off = 128; off > 0; off >>= 1) {
        if (t < off) s[t] += s[t + off];
        __syncthreads();
    }
    if (t == 0) blockSums[blockIdx.x] = s[0];
}

__global__ __launch_bounds__(256) void scanB(int* __restrict__ blockSums) {
    __shared__ int s[256];
    int t = threadIdx.x;
    int v = (t < 196) ? blockSums[t] : 0;
    s[t] = v;
    __syncthreads();
    for (int off = 1; off < 256; off <<= 1) {
        int x = (t >= off) ? s[t - off] : 0;
        __syncthreads();
        s[t] += x;
        __syncthreads();
    }
    if (t < 196) blockSums[t] = s[t] - v;   // exclusive
}

__global__ __launch_bounds__(256) void scanC(int* __restrict__ counts4,
                                             const int* __restrict__ blockSums) {
    __shared__ int s[256];
    int t = threadIdx.x;
    int idx = blockIdx.x * 256 + t;
    int c0 = counts4[idx], c1 = counts4[NNP + idx];
    int c2 = counts4[2 * NNP + idx], c3 = counts4[3 * NNP + idx];
    int v = c0 + c1 + c2 + c3;
    s[t] = v;
    __syncthreads();
    for (int off = 1; off < 256; off <<= 1) {
        int x = (t >= off) ? s[t - off] : 0;
        __syncthreads();
        s[t] += x;
        __syncthreads();
    }
    int st = blockSums[blockIdx.x] + s[t] - v;
    counts4[idx] = st;
    counts4[NNP + idx] = st + c0;
    counts4[2 * NNP + idx] = st + c0 + c1;
    counts4[3 * NNP + idx] = st + c0 + c1 + c2;
}

// scatter: 4 edges/thread -> 4 independent dst->startS->store chains
__global__ __launch_bounds__(256) void scatter_norank(const int* __restrict__ src,
                                                      const int* __restrict__ dst,
                                                      const int* __restrict__ rel,
                                                      const float* __restrict__ norm,
                                                      const int* __restrict__ startS,
                                                      const unsigned short* __restrict__ rank16,
                                                      uint2* __restrict__ recs) {
    int e4 = (blockIdx.x * 256 + threadIdx.x) * 4;
    if (e4 >= NE) return;                    // NE % 4 == 0 -> full groups
    int4 dv = *(const int4*)(dst + e4);
    int4 sv = *(const int4*)(src + e4);
    int4 rv = *(const int4*)(rel + e4);
    float4 nv = *(const float4*)(norm + e4);
    ushort4 rk = *(const ushort4*)(rank16 + e4);
    int p0 = startS[dv.x] + (int)rk.x;
    int p1 = startS[NNP + dv.y] + (int)rk.y;
    int p2 = startS[2 * NNP + dv.z] + (int)rk.z;
    int p3 = startS[3 * NNP + dv.w] + (int)rk.w;
    recs[p0] = make_uint2((unsigned int)(rv.x * NN + sv.x), __float_as_uint(nv.x));
    recs[p1] = make_uint2((unsigned int)(rv.y * NN + sv.y), __float_as_uint(nv.y));
    recs[p2] = make_uint2((unsigned int)(rv.z * NN + sv.z), __float_as_uint(nv.z));
    recs[p3] = make_uint2((unsigned int)(rv.w * NN + sv.w), __float_as_uint(nv.w));
}

// ---------------- phase 3: segmented reduction (unchanged) ----------------
__global__ __launch_bounds__(256) void seg_reduce(const int* __restrict__ start,
                                                  const uint2* __restrict__ recs,
                                                  const unsigned int* __restrict__ hb,
                                                  float* __restrict__ out) {
    int d = blockIdx.x * 4 + (threadIdx.x >> 6);   // wave-uniform
    if (d >= NN) return;
    int lane = threadIdx.x & 63;
    int beg = start[d], end = start[d + 1];
    float a0 = 0.f, a1 = 0.f;
    int i = beg;
    if ((i & 1) && i < end) {
        uint2 rc = recs[i];
        unsigned int u = hb[rc.x * 64u + lane];
        float nm = __uint_as_float(rc.y);
        a0 += bflo(u) * nm;
        a1 += bfhi(u) * nm;
        ++i;
    }
    for (; i + 7 < end; i += 8) {
        uint4 p0 = *(const uint4*)&recs[i];
        uint4 p1 = *(const uint4*)&recs[i + 2];
        uint4 p2 = *(const uint4*)&recs[i + 4];
        uint4 p3 = *(const uint4*)&recs[i + 6];
        unsigned int u0 = hb[p0.x * 64u + lane];
        unsigned int u1 = hb[p0.z * 64u + lane];
        unsigned int u2 = hb[p1.x * 64u + lane];
        unsigned int u3 = hb[p1.z * 64u + lane];
        unsigned int u4 = hb[p2.x * 64u + lane];
        unsigned int u5 = hb[p2.z * 64u + lane];
        unsigned int u6 = hb[p3.x * 64u + lane];
        unsigned int u7 = hb[p3.z * 64u + lane];
        float n0 = __uint_as_float(p0.y), n1 = __uint_as_float(p0.w);
        float n2 = __uint_as_float(p1.y), n3 = __uint_as_float(p1.w);
        float n4 = __uint_as_float(p2.y), n5 = __uint_as_float(p2.w);
        float n6 = __uint_as_float(p3.y), n7 = __uint_as_float(p3.w);
        a0 += bflo(u0) * n0 + bflo(u1) * n1 + bflo(u2) * n2 + bflo(u3) * n3;
        a1 += bfhi(u0) * n0 + bfhi(u1) * n1 + bfhi(u2) * n2 + bfhi(u3) * n3;
        a0 += bflo(u4) * n4 + bflo(u5) * n5 + bflo(u6) * n6 + bflo(u7) * n7;
        a1 += bfhi(u4) * n4 + bfhi(u5) * n5 + bfhi(u6) * n6 + bfhi(u7) * n7;
    }
    for (; i < end; ++i) {
        uint2 rc = recs[i];
        unsigned int u = hb[rc.x * 64u + lane];
        float nm = __uint_as_float(rc.y);
        a0 += bflo(u) * nm;
        a1 += bfhi(u) * nm;
    }
    *(float2*)(out + (size_t)d * 128 + lane * 2) = make_float2(a0, a1);
}

// ---------------- launch ---------------------------------------------------

extern "C" void kernel_launch(void* const* d_in, const int* in_sizes, int n_in,
                              void* d_out, int out_size, void* d_ws, size_t ws_size,
                              hipStream_t stream) {
    const int* node_ids = (const int*)d_in[0];
    const int* src      = (const int*)d_in[1];
    const int* dst      = (const int*)d_in[2];
    const int* rel      = (const int*)d_in[3];
    const float* norm   = (const float*)d_in[4];
    const float* emb    = (const float*)d_in[5];
    const float* W      = (const float*)d_in[6];
    float* out = (float*)d_out;

    char* ws = (char*)d_ws;
    unsigned short* h_rel = (unsigned short*)(ws);                 // 204,800,000 B
    unsigned short* h_bf  = (unsigned short*)(ws + 204800000);     //  12,800,000 B
    uint2* recs           = (uint2*)(ws + 204800000);              // ALIAS of h_bf
                                                                   // (written only after gemm_hrel)
    unsigned short* Wt    = (unsigned short*)(ws + 217600000);     //     524,288 B
    int* counts4          = (int*)(ws + 218124288);                //     802,816 B (4 planes)
    unsigned short* rank16= (unsigned short*)(ws + 218927104);     //   3,200,000 B
    int* blockSums        = (int*)(ws + 222127104);                //       1,024 B
    // total ~222.1 MB

    hipMemsetAsync(counts4, 0, 4 * NNP * sizeof(int), stream);

    prep_fused<<<HIST_BLKS + PREPH_BLKS + PREPW_BLKS, 256, 0, stream>>>(
        node_ids, emb, h_bf, W, Wt, dst, counts4, rank16);
    scanA<<<196, 256, 0, stream>>>(counts4, blockSums);
    scanB<<<1, 256, 0, stream>>>(blockSums);
    scanC<<<196, 256, 0, stream>>>(counts4, blockSums);

    gemm_hrel<<<dim3(391, 4), 256, 0, stream>>>(h_bf, Wt, h_rel);

    // recs aliases h_bf — must run after gemm_hrel (stream-serial: ok)
    scatter_norank<<<(NE / 4 + 255) / 256, 256, 0, stream>>>(src, dst, rel, norm,
                                                             counts4, rank16, recs);

    // start[] = counts4 plane 0 (scanC folded shard prefixes; sentinel at NN)
    seg_reduce<<<12500, 256, 0, stream>>>(counts4, recs,
                                          (const unsigned int*)h_rel, out);
}